// Round 4
// baseline (310.800 us; speedup 1.0000x reference)
//
#include <hip/hip_runtime.h>

#define B 8
#define T 128
#define U 64
#define V 512
#define NEG_INF (-1e30f)

// ---------------------------------------------------------------------------
// Kernel 1: for each (b,t,u) compute Z = logsumexp_v(e[b,t,v]+p[b,u,v]) and
// store blank_lp[b,t,u] = e0+p0-Z, label_lp[b,t,u] = e[lbl]+p[lbl]-Z.
// One block per (b,t); 4 waves; each wave owns u = wave, wave+4, ...
// e-row chunk (8 floats/lane) is register-resident across all u iterations.
// ---------------------------------------------------------------------------
__global__ __launch_bounds__(256) void lp_kernel(
    const float* __restrict__ em, const float* __restrict__ pr,
    const int* __restrict__ labels,
    float* __restrict__ blank_lp, float* __restrict__ label_lp)
{
    const int bt   = blockIdx.x;       // 0 .. B*T-1
    const int b    = bt / T;
    const int t    = bt % T;
    const int lane = threadIdx.x & 63;
    const int wave = threadIdx.x >> 6; // 0..3

    const float* erow = em + ((size_t)b * T + t) * V;
    // 8 consecutive e-values per lane (32B/lane, fully coalesced)
    const float4* e4 = (const float4*)(erow + lane * 8);
    const float4 ea = e4[0];
    const float4 eb = e4[1];
    float e[8] = {ea.x, ea.y, ea.z, ea.w, eb.x, eb.y, eb.z, eb.w};

    const float e0 = erow[0];

    for (int u = wave; u < U; u += 4) {
        const float* prow = pr + ((size_t)b * U + u) * V;
        const float4* p4 = (const float4*)(prow + lane * 8);
        const float4 pa = p4[0];
        const float4 pb = p4[1];
        float s[8];
        s[0] = e[0] + pa.x; s[1] = e[1] + pa.y;
        s[2] = e[2] + pa.z; s[3] = e[3] + pa.w;
        s[4] = e[4] + pb.x; s[5] = e[5] + pb.y;
        s[6] = e[6] + pb.z; s[7] = e[7] + pb.w;

        // wave-wide max (butterfly)
        float m = s[0];
        #pragma unroll
        for (int j = 1; j < 8; ++j) m = fmaxf(m, s[j]);
        #pragma unroll
        for (int d = 1; d < 64; d <<= 1) m = fmaxf(m, __shfl_xor(m, d));

        // wave-wide sum of exp(s - m)
        float sum = 0.0f;
        #pragma unroll
        for (int j = 0; j < 8; ++j) sum += expf(s[j] - m);
        #pragma unroll
        for (int d = 1; d < 64; d <<= 1) sum += __shfl_xor(sum, d);

        if (lane == 0) {
            const float Z = m + logf(sum);
            const size_t o = ((size_t)b * T + t) * U + u;
            blank_lp[o] = e0 + prow[0] - Z;
            if (u < U - 1) {
                const int lbl = labels[b * (U - 1) + u];
                label_lp[o] = erow[lbl] + prow[lbl] - Z;
            }
        }
    }
}

// ---------------------------------------------------------------------------
// Kernel 2: per-batch alpha recursion. Lane u holds column u (U == 64 == wave).
// Per t: c = exclusive prefix-sum of label_lp[t,:], then cumulative LSE scan
// of (a_top - c); a_next = c + cumLSE + blank_lp[t,:]. Only the score at
// (T_b-1, U_b) is needed.
// ---------------------------------------------------------------------------
__device__ __forceinline__ float logaddexp(float a, float bb) {
    float mx = fmaxf(a, bb);
    float mn = fminf(a, bb);
    return mx + log1pf(expf(mn - mx));
}

__global__ __launch_bounds__(64) void alpha_kernel(
    const float* __restrict__ blank_lp, const float* __restrict__ label_lp,
    const int* __restrict__ in_len, const int* __restrict__ lab_len,
    float* __restrict__ out)
{
    const int b  = blockIdx.x;
    const int u  = threadIdx.x;   // 0..63
    const int Tb = in_len[b];
    const int Ub = lab_len[b];

    float a = (u == 0) ? 0.0f : NEG_INF;  // a_top

    for (int t = 0; t < Tb; ++t) {
        const size_t o = ((size_t)b * T + t) * U + u;
        const float bl = blank_lp[o];
        float l = (u < U - 1) ? label_lp[o] : 0.0f;

        // inclusive prefix sum of l -> s; c[u] = s[u-1], c[0] = 0
        float s = l;
        #pragma unroll
        for (int d = 1; d < 64; d <<= 1) {
            float v = __shfl_up(s, d);
            if (u >= d) s += v;
        }
        float c = __shfl_up(s, 1);
        if (u == 0) c = 0.0f;

        // cumulative logsumexp scan of x = a - c
        float x = a - c;
        #pragma unroll
        for (int d = 1; d < 64; d <<= 1) {
            float v = __shfl_up(x, d);
            if (u >= d) x = logaddexp(x, v);
        }

        const float alpha_t = c + x;
        a = alpha_t + bl;  // a_next = alpha[t,u] + blank_lp[t,u]

        if (t == Tb - 1 && u == Ub) out[b] = -a;
    }
}

extern "C" void kernel_launch(void* const* d_in, const int* in_sizes, int n_in,
                              void* d_out, int out_size, void* d_ws, size_t ws_size,
                              hipStream_t stream) {
    const float* em      = (const float*)d_in[0];  // (B,T,V)
    const float* pr      = (const float*)d_in[1];  // (B,U,V)
    const int*   labels  = (const int*)d_in[2];    // (B,U-1)
    const int*   in_len  = (const int*)d_in[3];    // (B,)
    const int*   lab_len = (const int*)d_in[4];    // (B,)
    float* out = (float*)d_out;                    // (B,)

    float* blank_lp = (float*)d_ws;                       // B*T*U floats
    float* label_lp = blank_lp + (size_t)B * T * U;       // B*T*U floats (U-1 used)

    lp_kernel<<<B * T, 256, 0, stream>>>(em, pr, labels, blank_lp, label_lp);
    alpha_kernel<<<B, 64, 0, stream>>>(blank_lp, label_lp, in_len, lab_len, out);
}

// Round 5
// 105.423 us; speedup vs baseline: 2.9481x; 2.9481x over previous
//
#include <hip/hip_runtime.h>

#define B 8
#define T 128
#define U 64
#define V 512
#define NEG_INF (-1e30f)

// ---------------------------------------------------------------------------
// Kernel 1: for each (b,t,u) compute Z = logsumexp_v(e[b,t,v]+p[b,u,v]) and
// store blank_lp[b,t,u] = e0+p0-Z, label_lp[b,t,u] = e[lbl]+p[lbl]-Z.
// One block per (b,t); 4 waves; each wave owns u = wave, wave+4, ...
// ---------------------------------------------------------------------------
__global__ __launch_bounds__(256) void lp_kernel(
    const float* __restrict__ em, const float* __restrict__ pr,
    const int* __restrict__ labels,
    float* __restrict__ blank_lp, float* __restrict__ label_lp)
{
    const int bt   = blockIdx.x;       // 0 .. B*T-1
    const int b    = bt / T;
    const int t    = bt % T;
    const int lane = threadIdx.x & 63;
    const int wave = threadIdx.x >> 6; // 0..3

    const float* erow = em + ((size_t)b * T + t) * V;
    const float4* e4 = (const float4*)(erow + lane * 8);
    const float4 ea = e4[0];
    const float4 eb = e4[1];
    float e[8] = {ea.x, ea.y, ea.z, ea.w, eb.x, eb.y, eb.z, eb.w};

    const float e0 = erow[0];

    for (int u = wave; u < U; u += 4) {
        const float* prow = pr + ((size_t)b * U + u) * V;
        const float4* p4 = (const float4*)(prow + lane * 8);
        const float4 pa = p4[0];
        const float4 pb = p4[1];
        float s[8];
        s[0] = e[0] + pa.x; s[1] = e[1] + pa.y;
        s[2] = e[2] + pa.z; s[3] = e[3] + pa.w;
        s[4] = e[4] + pb.x; s[5] = e[5] + pb.y;
        s[6] = e[6] + pb.z; s[7] = e[7] + pb.w;

        float m = s[0];
        #pragma unroll
        for (int j = 1; j < 8; ++j) m = fmaxf(m, s[j]);
        #pragma unroll
        for (int d = 1; d < 64; d <<= 1) m = fmaxf(m, __shfl_xor(m, d));

        float sum = 0.0f;
        #pragma unroll
        for (int j = 0; j < 8; ++j) sum += expf(s[j] - m);
        #pragma unroll
        for (int d = 1; d < 64; d <<= 1) sum += __shfl_xor(sum, d);

        if (lane == 0) {
            const float Z = m + logf(sum);
            const size_t o = ((size_t)b * T + t) * U + u;
            blank_lp[o] = e0 + prow[0] - Z;
            if (u < U - 1) {
                const int lbl = labels[b * (U - 1) + u];
                label_lp[o] = erow[lbl] + prow[lbl] - Z;
            }
        }
    }
}

// ---------------------------------------------------------------------------
// Kernel 2: anti-diagonal wavefront alpha recursion, one block (1 wave) per b.
//   alpha[t,u] = LSE(alpha[t-1,u]+blank[t-1,u], alpha[t,u-1]+label[t,u-1])
// (mathematically identical to the reference's cumsum+cumlogsumexp scan).
// Diagonal d = t+u: lane u holds alpha[d-u, u]; per step 1 shfl_up + 1 LSE.
// Serial chain: Tb-1+Ub <= 190 steps (vs 128*12 cross-lane ops before).
// lp arrays staged to LDS (64 KB); diagonal reads are 2-way bank = free.
// ---------------------------------------------------------------------------
__device__ __forceinline__ float logaddexp(float a, float bb) {
    float mx = fmaxf(a, bb);
    float mn = fminf(a, bb);
    return mx + log1pf(expf(mn - mx));
}

__global__ __launch_bounds__(64) void alpha_kernel(
    const float* __restrict__ blank_lp, const float* __restrict__ label_lp,
    const int* __restrict__ in_len, const int* __restrict__ lab_len,
    float* __restrict__ out)
{
    __shared__ float blankL[T * U];   // 32 KB
    __shared__ float labelL[T * U];   // 32 KB (col U-1 unused)

    const int b = blockIdx.x;
    const int u = threadIdx.x;   // 0..63 == column
    const int Tb = in_len[b];
    const int Ub = lab_len[b];

    // stage both lp planes for this batch into LDS (coalesced float4)
    const float4* gb = (const float4*)(blank_lp + (size_t)b * T * U);
    const float4* gl = (const float4*)(label_lp + (size_t)b * T * U);
    float4* sb = (float4*)blankL;
    float4* sl = (float4*)labelL;
    #pragma unroll 4
    for (int i = u; i < (T * U) / 4; i += 64) {
        sb[i] = gb[i];
        sl[i] = gl[i];
    }
    __syncthreads();

    float a = (u == 0) ? 0.0f : NEG_INF;   // diagonal d=0: alpha[0,0]=0
    int tcur = -u;                          // t = d - u, starts at d=0
    const int dmax = (Tb - 1) + Ub;

    for (int d = 1; d <= dmax; ++d) {
        ++tcur;                             // tcur = d - u
        const float left_in = __shfl_up(a, 1);   // alpha[tcur, u-1] (old diag)
        const int tm1 = tcur - 1;

        // up: alpha[t-1,u] + blank[t-1,u]
        const int bi = (tm1 < 0 ? 0 : (tm1 > T - 1 ? T - 1 : tm1)) * U + u;
        float up = (tm1 >= 0) ? a + blankL[bi] : NEG_INF;

        // left: alpha[t,u-1] + label[t,u-1]
        const int li = (tcur < 0 ? 0 : (tcur > T - 1 ? T - 1 : tcur)) * U + (u - 1);
        float lf = (u >= 1 && tcur >= 0) ? left_in + labelL[li] : NEG_INF;

        const float na = logaddexp(up, lf);
        a = (tcur >= 0) ? na : NEG_INF;
    }

    if (u == Ub) out[b] = -(a + blankL[(Tb - 1) * U + u]);
}

extern "C" void kernel_launch(void* const* d_in, const int* in_sizes, int n_in,
                              void* d_out, int out_size, void* d_ws, size_t ws_size,
                              hipStream_t stream) {
    const float* em      = (const float*)d_in[0];  // (B,T,V)
    const float* pr      = (const float*)d_in[1];  // (B,U,V)
    const int*   labels  = (const int*)d_in[2];    // (B,U-1)
    const int*   in_len  = (const int*)d_in[3];    // (B,)
    const int*   lab_len = (const int*)d_in[4];    // (B,)
    float* out = (float*)d_out;                    // (B,)

    float* blank_lp = (float*)d_ws;                       // B*T*U floats
    float* label_lp = blank_lp + (size_t)B * T * U;       // B*T*U floats

    lp_kernel<<<B * T, 256, 0, stream>>>(em, pr, labels, blank_lp, label_lp);
    alpha_kernel<<<B, 64, 0, stream>>>(blank_lp, label_lp, in_len, lab_len, out);
}

// Round 6
// 46.996 us; speedup vs baseline: 6.6134x; 2.2432x over previous
//
#include <hip/hip_runtime.h>

#define B 8
#define T 128
#define U 64
#define V 512
#define NEG_INF (-1e30f)

// ---------------------------------------------------------------------------
// Kernel 1: for each (b,t,u): Z = logsumexp_v(e[b,t,v]+p[b,u,v]);
// blank_lp[b,t,u] = e0+p0-Z; label_lp[b,t,u] = e[lbl]+p[lbl]-Z.
// One block per (b,t); 8 waves (512 thr) -> 32 waves/CU (grid is 1024 blocks).
// Online (m,s) butterfly: 6 steps, 2 parallel shfls/step, vs 12 dependent.
// ---------------------------------------------------------------------------
__global__ __launch_bounds__(512) void lp_kernel(
    const float* __restrict__ em, const float* __restrict__ pr,
    const int* __restrict__ labels,
    float* __restrict__ blank_lp, float* __restrict__ label_lp)
{
    const int bt   = blockIdx.x;       // 0 .. B*T-1
    const int b    = bt / T;
    const int t    = bt % T;
    const int lane = threadIdx.x & 63;
    const int wave = threadIdx.x >> 6; // 0..7

    const float* erow = em + ((size_t)b * T + t) * V;
    const float4* e4 = (const float4*)(erow + lane * 8);
    const float4 ea = e4[0];
    const float4 eb = e4[1];
    float e[8] = {ea.x, ea.y, ea.z, ea.w, eb.x, eb.y, eb.z, eb.w};

    const float e0 = erow[0];

    for (int u = wave; u < U; u += 8) {
        const float* prow = pr + ((size_t)b * U + u) * V;
        const float4* p4 = (const float4*)(prow + lane * 8);
        const float4 pa = p4[0];
        const float4 pb = p4[1];
        float s[8];
        s[0] = e[0] + pa.x; s[1] = e[1] + pa.y;
        s[2] = e[2] + pa.z; s[3] = e[3] + pa.w;
        s[4] = e[4] + pb.x; s[5] = e[5] + pb.y;
        s[6] = e[6] + pb.z; s[7] = e[7] + pb.w;

        // per-lane max (tree) and exp-sum
        float m01 = fmaxf(s[0], s[1]), m23 = fmaxf(s[2], s[3]);
        float m45 = fmaxf(s[4], s[5]), m67 = fmaxf(s[6], s[7]);
        float m = fmaxf(fmaxf(m01, m23), fmaxf(m45, m67));
        float sum = 0.0f;
        #pragma unroll
        for (int j = 0; j < 8; ++j) sum += __expf(s[j] - m);

        // online (m,s) butterfly across 64 lanes: 6 steps
        #pragma unroll
        for (int d = 1; d < 64; d <<= 1) {
            const float mo = __shfl_xor(m, d);
            const float so = __shfl_xor(sum, d);
            const float mn = fmaxf(m, mo);
            sum = sum * __expf(m - mn) + so * __expf(mo - mn);
            m = mn;
        }

        if (lane == 0) {
            const float Z = m + __logf(sum);
            const size_t o = ((size_t)b * T + t) * U + u;
            blank_lp[o] = e0 + prow[0] - Z;
            if (u < U - 1) {
                const int lbl = labels[b * (U - 1) + u];
                label_lp[o] = erow[lbl] + prow[lbl] - Z;
            }
        }
    }
}

// ---------------------------------------------------------------------------
// Kernel 2: anti-diagonal wavefront alpha recursion, 1 wave per batch.
//   alpha[t,u] = LSE(alpha[t-1,u]+blank[t-1,u], alpha[t,u-1]+label[t,u-1])
// Lane u owns column u; diagonal d = t+u. Per step: 1 shfl_up + fast LSE
// (__expf/__logf, ~9 dependent VALU ops). LDS read addresses depend only on
// (d,u) so they pipeline under the previous step's LSE.
// Out-of-lattice cells (t>Tb-1) compute junk but can only flow to other
// out-of-lattice cells, never into the (Tb-1, Ub) output.
// ---------------------------------------------------------------------------
__global__ __launch_bounds__(64) void alpha_kernel(
    const float* __restrict__ blank_lp, const float* __restrict__ label_lp,
    const int* __restrict__ in_len, const int* __restrict__ lab_len,
    float* __restrict__ out)
{
    __shared__ float blankL[T * U];   // 32 KB
    __shared__ float labelL[T * U];   // 32 KB (col U-1 never read)

    const int b = blockIdx.x;
    const int u = threadIdx.x;   // 0..63 == column
    const int Tb = in_len[b];
    const int Ub = lab_len[b];

    // stage both lp planes for this batch into LDS (coalesced float4)
    const float4* gb = (const float4*)(blank_lp + (size_t)b * T * U);
    const float4* gl = (const float4*)(label_lp + (size_t)b * T * U);
    float4* sb = (float4*)blankL;
    float4* sl = (float4*)labelL;
    #pragma unroll 4
    for (int i = u; i < (T * U) / 4; i += 64) {
        sb[i] = gb[i];
        sl[i] = gl[i];
    }
    __syncthreads();

    const int lcol = (u == 0) ? 0 : (u - 1);
    float a = (u == 0) ? 0.0f : NEG_INF;   // diagonal d=0: alpha[0,0]=0
    const int dmax = (Tb - 1) + Ub;

    #pragma unroll 2
    for (int d = 1; d <= dmax; ++d) {
        const int tc = d - u;        // t on this diagonal for this lane
        const int tm = tc - 1;
        // clamped addresses (junk reads are masked by the ternaries below)
        const int bi = (tm < 0 ? 0 : (tm > T - 1 ? T - 1 : tm)) * U + u;
        const int li = (tc < 0 ? 0 : (tc > T - 1 ? T - 1 : tc)) * U + lcol;
        const float blk = blankL[bi];
        const float lbl = labelL[li];

        const float left = __shfl_up(a, 1);          // alpha[tc, u-1]
        const float up = (tm >= 0) ? (a + blk) : NEG_INF;
        const float lf = (u >= 1 && tc >= 0) ? (left + lbl) : NEG_INF;

        // fast LSE: mx + log(1 + exp(mn-mx))
        const float mx = fmaxf(up, lf);
        const float dd = fminf(up, lf) - mx;         // <= 0, finite
        const float na = mx + __logf(1.0f + __expf(dd));
        a = (tc >= 0) ? na : a;
    }

    if (u == Ub) out[b] = -(a + blankL[(Tb - 1) * U + u]);
}

extern "C" void kernel_launch(void* const* d_in, const int* in_sizes, int n_in,
                              void* d_out, int out_size, void* d_ws, size_t ws_size,
                              hipStream_t stream) {
    const float* em      = (const float*)d_in[0];  // (B,T,V)
    const float* pr      = (const float*)d_in[1];  // (B,U,V)
    const int*   labels  = (const int*)d_in[2];    // (B,U-1)
    const int*   in_len  = (const int*)d_in[3];    // (B,)
    const int*   lab_len = (const int*)d_in[4];    // (B,)
    float* out = (float*)d_out;                    // (B,)

    float* blank_lp = (float*)d_ws;                       // B*T*U floats
    float* label_lp = blank_lp + (size_t)B * T * U;       // B*T*U floats

    lp_kernel<<<B * T, 512, 0, stream>>>(em, pr, labels, blank_lp, label_lp);
    alpha_kernel<<<B, 64, 0, stream>>>(blank_lp, label_lp, in_len, lab_len, out);
}